// Round 3
// baseline (12848.192 us; speedup 1.0000x reference)
//
#include <hip/hip_runtime.h>
#include <stdint.h>

// ---------------------------------------------------------------------------
// Seq2Seq (V=10000, E=256, H=512, B=64, T=128), all fp32.
// Output rows are one-hot: only argmax(logits + gumbel) matters, needing
// bit-exact JAX threefry2x32 replication.
// RNG variant ladder: R1 partitionable-o1 FAILED; R2 legacy split FAILED;
// R3 partitionable XOR (bits1 ^ bits2 — the 8/16/32-bit fold in
// _threefry_random_bits_partitionable).  R4 fallback: partitionable-o0.
// ---------------------------------------------------------------------------

#define RNG_VARIANT 2   // 0=legacy split, 1=part o1, 2=part o0^o1, 3=part o0

__device__ __forceinline__ void threefry2x32(uint32_t k0, uint32_t k1,
                                             uint32_t x0, uint32_t x1,
                                             uint32_t& o0, uint32_t& o1)
{
  const uint32_t k2 = k0 ^ k1 ^ 0x1BD11BDAu;
  x0 += k0; x1 += k1;
#define TF_R(r) x0 += x1; x1 = (x1 << r) | (x1 >> (32 - r)); x1 ^= x0;
  TF_R(13) TF_R(15) TF_R(26) TF_R(6)
  x0 += k1; x1 += k2 + 1u;
  TF_R(17) TF_R(29) TF_R(16) TF_R(24)
  x0 += k2; x1 += k0 + 2u;
  TF_R(13) TF_R(15) TF_R(26) TF_R(6)
  x0 += k0; x1 += k1 + 3u;
  TF_R(17) TF_R(29) TF_R(16) TF_R(24)
  x0 += k1; x1 += k2 + 4u;
  TF_R(13) TF_R(15) TF_R(26) TF_R(6)
  x0 += k2; x1 += k0 + 5u;
#undef TF_R
  o0 = x0; o1 = x1;
}

// uniform [0,1) float for flat index i of a (T,B,V)=81,920,000-element array,
// key = jax.random.key(seed) -> (0, seed)
__device__ __forceinline__ float jax_uniform(uint32_t seed, uint32_t i)
{
  uint32_t bits;
#if RNG_VARIANT == 0
  // legacy: split halves; i<half -> o0 of (i, i+half); else o1 of (i-half, i)
  const uint32_t HALF = 40960000u;
  const bool lo = (i < HALF);
  const uint32_t x0 = lo ? i : (i - HALF);
  uint32_t o0, o1;
  threefry2x32(0u, seed, x0, x0 + HALF, o0, o1);
  bits = lo ? o0 : o1;
#else
  // partitionable: counts = iota(u64); hi word = 0 (size < 2^32)
  uint32_t o0, o1;
  threefry2x32(0u, seed, 0u, i, o0, o1);
#if RNG_VARIANT == 1
  bits = o1;
#elif RNG_VARIANT == 2
  bits = o0 ^ o1;
#else
  bits = o0;
#endif
#endif
  return __uint_as_float(0x3F800000u | (bits >> 9)) - 1.0f;
}

// ---------------------------------------------------------------------------
// Generic fp32 GEMM: C[m,n] = sum_k A(m,k) * W[n,k] + bias[n]
// amode 0: A(m,k) = embed[ids[(m&63)*128 + (m>>6)]][k]   (gather, row-major K)
// amode 1: A(m,k) = base[(m>>6)*K*64 + k*64 + (m&63)]     ([t][k][b] packed)
// cmode 0: row-major C[m*N + n]
// cmode 1: packed   C[(m>>6)*N*64 + n*64 + (m&63)]
// M multiple of 64; K multiple of 16; N bound-checked.
// ---------------------------------------------------------------------------
__global__ __launch_bounds__(256)
void gemm_kernel(const float* __restrict__ A, const int* __restrict__ ids,
                 const float* __restrict__ W, const float* __restrict__ bias,
                 float* __restrict__ C, int M, int N, int K, int amode, int cmode)
{
  __shared__ __align__(16) float As[16][64];
  __shared__ __align__(16) float Bs[16][64];
  const int tid = threadIdx.x;
  const int tx = tid & 15;       // n quad
  const int ty = tid >> 4;       // m quad
  const int m0 = blockIdx.x * 64;
  const int n0 = blockIdx.y * 64;
  const int lm = tid >> 2;       // 0..63 loader row
  const int kq = tid & 3;        // 0..3 loader k-quad

  const float* arow = nullptr;
  if (amode == 0) {
    const int m = m0 + lm;
    const int token = ids[(m & 63) * 128 + (m >> 6)];
    arow = A + (size_t)token * K;
  }
  const int nW = n0 + lm;
  const bool wok = (nW < N);
  const float* wrow = W + (size_t)(wok ? nW : 0) * K;

  float acc[4][4] = {{0.f,0.f,0.f,0.f},{0.f,0.f,0.f,0.f},
                     {0.f,0.f,0.f,0.f},{0.f,0.f,0.f,0.f}};

  for (int k0 = 0; k0 < K; k0 += 16) {
    if (amode == 0) {
      const float4 av = *(const float4*)(arow + k0 + kq * 4);
      As[kq*4+0][lm] = av.x; As[kq*4+1][lm] = av.y;
      As[kq*4+2][lm] = av.z; As[kq*4+3][lm] = av.w;
    } else {
      ((float4*)&As[0][0])[tid] =
          ((const float4*)(A + (size_t)m0 * K + (size_t)k0 * 64))[tid];
    }
    float4 wv = make_float4(0.f, 0.f, 0.f, 0.f);
    if (wok) wv = *(const float4*)(wrow + k0 + kq * 4);
    Bs[kq*4+0][lm] = wv.x; Bs[kq*4+1][lm] = wv.y;
    Bs[kq*4+2][lm] = wv.z; Bs[kq*4+3][lm] = wv.w;
    __syncthreads();
#pragma unroll
    for (int kk = 0; kk < 16; ++kk) {
      const float4 a4 = *(const float4*)&As[kk][ty * 4];
      const float4 b4 = *(const float4*)&Bs[kk][tx * 4];
      acc[0][0] += a4.x*b4.x; acc[0][1] += a4.x*b4.y; acc[0][2] += a4.x*b4.z; acc[0][3] += a4.x*b4.w;
      acc[1][0] += a4.y*b4.x; acc[1][1] += a4.y*b4.y; acc[1][2] += a4.y*b4.z; acc[1][3] += a4.y*b4.w;
      acc[2][0] += a4.z*b4.x; acc[2][1] += a4.z*b4.y; acc[2][2] += a4.z*b4.z; acc[2][3] += a4.z*b4.w;
      acc[3][0] += a4.w*b4.x; acc[3][1] += a4.w*b4.y; acc[3][2] += a4.w*b4.z; acc[3][3] += a4.w*b4.w;
    }
    __syncthreads();
  }

  if (cmode == 0) {
#pragma unroll
    for (int i = 0; i < 4; ++i) {
      const int m = m0 + ty * 4 + i;
#pragma unroll
      for (int j = 0; j < 4; ++j) {
        const int n = n0 + tx * 4 + j;
        if (n < N) C[(size_t)m * N + n] = acc[i][j] + bias[n];
      }
    }
  } else {
    float* cb = C + (size_t)m0 * N;   // == (m0/64) * (N*64)
#pragma unroll
    for (int j = 0; j < 4; ++j) {
      const int n = n0 + tx * 4 + j;
      if (n < N) {
        const float bv = bias[n];
#pragma unroll
        for (int i = 0; i < 4; ++i)
          cb[(size_t)n * 64 + ty * 4 + i] = acc[i][j] + bv;
      }
    }
  }
}

// ---------------------------------------------------------------------------
// One LSTM recurrence step.  Layouts: Xg (this step) [2048 cols][64 b] with
// col = gate*512 + u (gates i,f,g,o);  h,c: [512 u][64 b];  Whh: [2048][512].
// Grid 256 blocks x 128 threads; block handles 2 hidden units x 64 batches.
// ---------------------------------------------------------------------------
__global__ __launch_bounds__(128)
void lstm_step_kernel(const float* __restrict__ Xg,
                      const float* __restrict__ hprev,
                      const float* __restrict__ Whh,
                      float* __restrict__ cstate,
                      float* __restrict__ hout)
{
  __shared__ __align__(16) float ws[8][512];   // rows: ui*4 + gate
  __shared__ __align__(16) float hs[4096];     // [64 k][64 b] chunk
  const int tid = threadIdx.x;
  const int b = tid & 63;
  const int ui = tid >> 6;            // 0..1
  const int U0 = blockIdx.x * 2;
  const int u = U0 + ui;

  // stage Whh rows (16 threads per row, 8 rows)
  {
    const int r = tid >> 4;           // 0..7
    const int lui = r >> 2, lg = r & 3;
    const float* wrow = Whh + (size_t)(lg * 512 + U0 + lui) * 512;
    const int kq = tid & 15;
#pragma unroll
    for (int i = 0; i < 8; ++i) {
      const int k = kq * 4 + i * 64;
      *(float4*)&ws[r][k] = *(const float4*)(wrow + k);
    }
  }

  // prefetch x-part gates & old c
  const float x_i = Xg[(size_t)(0 * 512 + u) * 64 + b];
  const float x_f = Xg[(size_t)(1 * 512 + u) * 64 + b];
  const float x_g = Xg[(size_t)(2 * 512 + u) * 64 + b];
  const float x_o = Xg[(size_t)(3 * 512 + u) * 64 + b];
  const float c_old = cstate[(size_t)u * 64 + b];

  float4 pre[8];
#pragma unroll
  for (int i = 0; i < 8; ++i) pre[i] = ((const float4*)hprev)[tid + 128 * i];

  float a0 = 0.f, a1 = 0.f, a2 = 0.f, a3 = 0.f;
  for (int kc = 0; kc < 8; ++kc) {
    __syncthreads();                      // prev compute done (and ws ready)
#pragma unroll
    for (int i = 0; i < 8; ++i) ((float4*)hs)[tid + 128 * i] = pre[i];
    __syncthreads();
    if (kc < 7) {
#pragma unroll
      for (int i = 0; i < 8; ++i)
        pre[i] = ((const float4*)hprev)[(kc + 1) * 1024 + tid + 128 * i];
    }
    const int kb = kc * 64;
#pragma unroll
    for (int kg = 0; kg < 16; ++kg) {
      const float h0 = hs[(kg * 4 + 0) * 64 + b];
      const float h1 = hs[(kg * 4 + 1) * 64 + b];
      const float h2 = hs[(kg * 4 + 2) * 64 + b];
      const float h3 = hs[(kg * 4 + 3) * 64 + b];
      const float4 w0 = *(const float4*)&ws[ui * 4 + 0][kb + kg * 4];
      const float4 w1 = *(const float4*)&ws[ui * 4 + 1][kb + kg * 4];
      const float4 w2 = *(const float4*)&ws[ui * 4 + 2][kb + kg * 4];
      const float4 w3 = *(const float4*)&ws[ui * 4 + 3][kb + kg * 4];
      a0 += h0 * w0.x + h1 * w0.y + h2 * w0.z + h3 * w0.w;
      a1 += h0 * w1.x + h1 * w1.y + h2 * w1.z + h3 * w1.w;
      a2 += h0 * w2.x + h1 * w2.y + h2 * w2.z + h3 * w2.w;
      a3 += h0 * w3.x + h1 * w3.y + h2 * w3.z + h3 * w3.w;
    }
  }

  const float zi = x_i + a0, zf = x_f + a1, zg = x_g + a2, zo = x_o + a3;
  const float I = 1.0f / (1.0f + expf(-zi));
  const float F = 1.0f / (1.0f + expf(-zf));
  const float G = tanhf(zg);
  const float O = 1.0f / (1.0f + expf(-zo));
  const float cn = F * c_old + I * G;
  cstate[(size_t)u * 64 + b] = cn;
  hout[(size_t)u * 64 + b] = O * tanhf(cn);
}

// ---------------------------------------------------------------------------
// Per-(b,t) token selection: argmax_v of (logits-or-U42) + gumbel(U7).
// logits rows are (j*64+b)*10000 with j = t-1.
// ---------------------------------------------------------------------------
__global__ __launch_bounds__(256)
void token_kernel(const int* __restrict__ input_ids,
                  const int* __restrict__ mask,
                  const float* __restrict__ logits,
                  int* __restrict__ tokens)
{
  const int row = blockIdx.x;        // b*128 + t
  const int b = row >> 7;
  const int t = row & 127;
  const int tid = threadIdx.x;
  const int mk = mask[row];
  if (mk == 0) {
    if (tid == 0) tokens[row] = input_ids[row];
    return;
  }
  int r = 0;                         // idx[b,t] = # masked positions before t
  for (int s = 0; s < t; ++s) r += mask[(b << 7) + s];

  const uint32_t base7  = (uint32_t)(r * 64 + b) * 10000u;
  const uint32_t base42 = (uint32_t)b * 10000u;
  const size_t loff = (t >= 1) ? (size_t)((t - 1) * 64 + b) * 10000u : 0u;
  const float* lrow = logits + loff;

  float best = -3.0e38f;
  int bestv = 0;
  for (int v = tid; v < 10000; v += 256) {
    const float u7 = jax_uniform(7u, base7 + (uint32_t)v);
    const float g = -logf(-logf(u7 + 1e-20f) + 1e-20f);
    float z = (t >= 1) ? lrow[v] : jax_uniform(42u, base42 + (uint32_t)v);
    z += g;
    if (z > best) { best = z; bestv = v; }   // within-thread: ascending v, first wins
  }
  __shared__ float sv[256];
  __shared__ int sidx[256];
  sv[tid] = best; sidx[tid] = bestv;
  __syncthreads();
  for (int s = 128; s > 0; s >>= 1) {
    if (tid < s) {
      const float ov = sv[tid + s]; const int oi = sidx[tid + s];
      if (ov > sv[tid] || (ov == sv[tid] && oi < sidx[tid])) {
        sv[tid] = ov; sidx[tid] = oi;
      }
    }
    __syncthreads();
  }
  if (tid == 0) tokens[row] = sidx[0];
}

__global__ __launch_bounds__(256)
void onehot_kernel(const int* __restrict__ tokens, float* __restrict__ out)
{
  const int row = blockIdx.x;
  const int tok = tokens[row];
  float4* orow = (float4*)(out + (size_t)row * 10000);
  for (int q = threadIdx.x; q < 2500; q += 256) {
    float4 v = make_float4(0.f, 0.f, 0.f, 0.f);
    const int v0 = q << 2;
    const unsigned d = (unsigned)(tok - v0);
    if (d < 4u) ((float*)&v)[d] = 1.0f;
    orow[q] = v;
  }
}

__global__ __launch_bounds__(256)
void zero_kernel(float* __restrict__ p, int n)
{
  const int i = blockIdx.x * 256 + threadIdx.x;
  if (i < n) p[i] = 0.f;
}

// ---------------------------------------------------------------------------
extern "C" void kernel_launch(void* const* d_in, const int* in_sizes, int n_in,
                              void* d_out, int out_size, void* d_ws, size_t ws_size,
                              hipStream_t stream)
{
  const int*   input_ids = (const int*)d_in[0];
  const int*   mask      = (const int*)d_in[1];
  const float* enc_embed = (const float*)d_in[3];
  const float* enc_Wih0  = (const float*)d_in[4];
  const float* enc_Whh0  = (const float*)d_in[5];
  const float* enc_b0    = (const float*)d_in[6];
  const float* enc_Wih1  = (const float*)d_in[7];
  const float* enc_Whh1  = (const float*)d_in[8];
  const float* enc_b1    = (const float*)d_in[9];
  const float* dec_embed = (const float*)d_in[10];
  const float* dec_Wih0  = (const float*)d_in[11];
  const float* dec_Whh0  = (const float*)d_in[12];
  const float* dec_b0    = (const float*)d_in[13];
  const float* dec_Wih1  = (const float*)d_in[14];
  const float* dec_Whh1  = (const float*)d_in[15];
  const float* dec_b1    = (const float*)d_in[16];
  const float* dec_Wout  = (const float*)d_in[17];
  const float* dec_bout  = (const float*)d_in[18];

  float* outf = (float*)d_out;
  float* Xg   = outf;                 // 8192*2048 fp32 scratch inside d_out;
                                      // dead before logits GEMM overwrites it.
  float* seqA = (float*)d_ws;         // 128 * 32768 floats ([t][512][64])
  float* zbuf = seqA + (size_t)128 * 32768;
  float* cA   = zbuf + 32768;
  float* cB   = cA + 32768;
  float* hp0  = cB + 32768;
  float* hp1  = hp0 + 32768;
  int* tokens = (int*)(hp1 + 32768);

  zero_kernel<<<384, 256, 0, stream>>>(zbuf, 3 * 32768);   // zbuf, cA, cB

  // ---- encoder layer 0: x-part GEMM then 128 recurrence steps -> seqA
  gemm_kernel<<<dim3(128, 32), 256, 0, stream>>>(
      enc_embed, input_ids, enc_Wih0, enc_b0, Xg, 8192, 2048, 256, 0, 1);
  for (int t = 0; t < 128; ++t) {
    const float* hi = (t == 0) ? zbuf : (seqA + (size_t)(t - 1) * 32768);
    lstm_step_kernel<<<256, 128, 0, stream>>>(
        Xg + (size_t)t * 131072, hi, enc_Whh0, cA, seqA + (size_t)t * 32768);
  }

  // ---- encoder layer 1 (only final state needed; ping-pong h)
  gemm_kernel<<<dim3(128, 32), 256, 0, stream>>>(
      seqA, nullptr, enc_Wih1, enc_b1, Xg, 8192, 2048, 512, 1, 1);
  for (int t = 0; t < 128; ++t) {
    const float* hi = (t == 0) ? zbuf : ((t & 1) ? hp0 : hp1);
    float* ho = (t & 1) ? hp1 : hp0;                       // t=127 -> hp1
    lstm_step_kernel<<<256, 128, 0, stream>>>(
        Xg + (size_t)t * 131072, hi, enc_Whh1, cB, ho);
  }

  // ---- decoder layer 0: init (h,c) = enc L0 finals (seqA[127], cA)
  gemm_kernel<<<dim3(127, 32), 256, 0, stream>>>(
      dec_embed, input_ids, dec_Wih0, dec_b0, Xg, 8128, 2048, 256, 0, 1);
  for (int j = 0; j < 127; ++j) {
    const float* hi = (j == 0) ? (seqA + (size_t)127 * 32768)
                               : (seqA + (size_t)(j - 1) * 32768);
    lstm_step_kernel<<<256, 128, 0, stream>>>(
        Xg + (size_t)j * 131072, hi, dec_Whh0, cA, seqA + (size_t)j * 32768);
  }

  // ---- decoder layer 1: init (h,c) = enc L1 finals (hp1, cB); reuse seqA
  gemm_kernel<<<dim3(127, 32), 256, 0, stream>>>(
      seqA, nullptr, dec_Wih1, dec_b1, Xg, 8128, 2048, 512, 1, 1);
  for (int j = 0; j < 127; ++j) {
    const float* hi = (j == 0) ? hp1 : (seqA + (size_t)(j - 1) * 32768);
    lstm_step_kernel<<<256, 128, 0, stream>>>(
        Xg + (size_t)j * 131072, hi, dec_Whh1, cB, seqA + (size_t)j * 32768);
  }

  // ---- output projection: logits (8128 x 10000) into d_out (row-major)
  gemm_kernel<<<dim3(127, 157), 256, 0, stream>>>(
      seqA, nullptr, dec_Wout, dec_bout, outf, 8128, 10000, 512, 1, 0);

  // ---- per-(b,t) token via gumbel-argmax, then one-hot fill of d_out
  token_kernel<<<8192, 256, 0, stream>>>(input_ids, mask, outf, tokens);
  onehot_kernel<<<8192, 256, 0, stream>>>(tokens, outf);
}

// Round 4
// 12063.013 us; speedup vs baseline: 1.0651x; 1.0651x over previous
//
#include <hip/hip_runtime.h>
#include <stdint.h>

// ---------------------------------------------------------------------------
// Seq2Seq (V=10000, E=256, H=512, B=64, T=128).
// Output rows are one-hot: only argmax(logits + gumbel) matters (bit-exact
// JAX threefry, partitionable XOR variant — verified R3, absmax 0.0).
// R4: GEMMs -> split-bf16 3-pass MFMA (hi*hi + hi*lo + lo*hi, fp32 acc);
//     logits GEMM fused with gumbel-argmax (no 325MB materialization);
//     recurrence kernel untouched (verified).
// ---------------------------------------------------------------------------

typedef short bf16x8 __attribute__((ext_vector_type(8)));
typedef float f32x4 __attribute__((ext_vector_type(4)));

__device__ __forceinline__ void threefry2x32(uint32_t k0, uint32_t k1,
                                             uint32_t x0, uint32_t x1,
                                             uint32_t& o0, uint32_t& o1)
{
  const uint32_t k2 = k0 ^ k1 ^ 0x1BD11BDAu;
  x0 += k0; x1 += k1;
#define TF_R(r) x0 += x1; x1 = (x1 << r) | (x1 >> (32 - r)); x1 ^= x0;
  TF_R(13) TF_R(15) TF_R(26) TF_R(6)
  x0 += k1; x1 += k2 + 1u;
  TF_R(17) TF_R(29) TF_R(16) TF_R(24)
  x0 += k2; x1 += k0 + 2u;
  TF_R(13) TF_R(15) TF_R(26) TF_R(6)
  x0 += k0; x1 += k1 + 3u;
  TF_R(17) TF_R(29) TF_R(16) TF_R(24)
  x0 += k1; x1 += k2 + 4u;
  TF_R(13) TF_R(15) TF_R(26) TF_R(6)
  x0 += k2; x1 += k0 + 5u;
#undef TF_R
  o0 = x0; o1 = x1;
}

// jax.random.uniform bits, partitionable scheme, 32-bit = o0 ^ o1 (verified R3)
__device__ __forceinline__ float jax_uniform(uint32_t seed, uint32_t i)
{
  uint32_t o0, o1;
  threefry2x32(0u, seed, 0u, i, o0, o1);
  const uint32_t bits = o0 ^ o1;
  return __uint_as_float(0x3F800000u | (bits >> 9)) - 1.0f;
}

__device__ __forceinline__ ushort f2bf(float x)   // fp32 -> bf16 bits, RNE
{
  const uint32_t u = __float_as_uint(x);
  const uint32_t r = u + 0x7FFFu + ((u >> 16) & 1u);
  return (ushort)(r >> 16);
}
__device__ __forceinline__ float bf2f(ushort b)
{
  return __uint_as_float(((uint32_t)b) << 16);
}

__device__ __forceinline__ unsigned long long packkey(float f, int n)
{
  uint32_t u = __float_as_uint(f);
  u = (u & 0x80000000u) ? ~u : (u | 0x80000000u);   // order-preserving map
  return ((unsigned long long)u << 32) | (uint32_t)(0x7FFFFFFF - n);
}

// ---------------------------------------------------------------------------
// split fp32 -> (bf16 hi, bf16 lo)
// ---------------------------------------------------------------------------
__global__ __launch_bounds__(256)
void split_kernel(const float* __restrict__ src, ushort* __restrict__ hi,
                  ushort* __restrict__ lo, int n)
{
  const int i = blockIdx.x * 256 + threadIdx.x;
  if (i < n) {
    const float v = src[i];
    const ushort h = f2bf(v);
    hi[i] = h;
    lo[i] = f2bf(v - bf2f(h));
  }
}

// ---------------------------------------------------------------------------
// seq [t][k=512][b=64] fp32  ->  T hi/lo [t*64+b][k] bf16 (row-major M x K)
// block = (t, kc): kc selects a 128-wide k slab.
// ---------------------------------------------------------------------------
__global__ __launch_bounds__(256)
void transpose_split_kernel(const float* __restrict__ seq,
                            ushort* __restrict__ Thi, ushort* __restrict__ Tlo)
{
  __shared__ float tile[128][65];
  const int t = blockIdx.x >> 2;
  const int kc = blockIdx.x & 3;
  const int tid = threadIdx.x;
  const float* sbase = seq + (size_t)t * 32768 + (size_t)kc * 128 * 64;
#pragma unroll
  for (int it = 0; it < 32; ++it) {
    const int idx = it * 256 + tid;
    tile[idx >> 6][idx & 63] = sbase[idx];
  }
  __syncthreads();
#pragma unroll
  for (int it = 0; it < 32; ++it) {
    const int idx = it * 256 + tid;
    const int b = idx >> 7, k = idx & 127;
    const float v = tile[k][b];
    const size_t o = ((size_t)t * 64 + b) * 512 + kc * 128 + k;
    const ushort h = f2bf(v);
    Thi[o] = h;
    Tlo[o] = f2bf(v - bf2f(h));
  }
}

// ---------------------------------------------------------------------------
// Split-bf16 MFMA GEMM: C[m,n] = sum_k A[m,k]*W[n,k] (+bias), A,W pre-split.
// 128x128 block tile, 4 waves (2x2), 16 MFMA-tiles/wave, 3 MFMA per tile per
// 32-k chunk. Fragments loaded 16B/lane directly from global (L2-resident).
// GATHER: A row = embed[ids[(m&63)*128 + (m>>6)]].
// FUSED=0: store Xg packed [t][n][b] (+bias).  FUSED=1: gumbel-argmax epilogue.
// ---------------------------------------------------------------------------
template <int GATHER, int FUSED>
__global__ __launch_bounds__(256)
void gemm_split(const ushort* __restrict__ Ahi, const ushort* __restrict__ Alo,
                const int* __restrict__ ids,
                const ushort* __restrict__ Whi, const ushort* __restrict__ Wlo,
                const float* __restrict__ bias, float* __restrict__ Xg,
                const int* __restrict__ mask, const int* __restrict__ idxmap,
                unsigned long long* __restrict__ keys,
                int M, int N, int K)
{
  const int tid = threadIdx.x;
  const int wid = tid >> 6, lane = tid & 63;
  const int lm = lane & 15, quad = lane >> 4;
  const int m0 = blockIdx.x * 128 + (wid >> 1) * 64;
  const int n0 = blockIdx.y * 128 + (wid & 1) * 64;
  const int koff = quad * 8;

  size_t offA[4];
#pragma unroll
  for (int mi = 0; mi < 4; ++mi) {
    int m = m0 + mi * 16 + lm;
    int mc = m < M ? m : (M - 1);
    if (GATHER) {
      const int tok = ids[(mc & 63) * 128 + (mc >> 6)];
      offA[mi] = (size_t)tok * K;
    } else {
      offA[mi] = (size_t)mc * K;
    }
  }
  size_t offB[4];
#pragma unroll
  for (int ni = 0; ni < 4; ++ni) {
    int n = n0 + ni * 16 + lm;
    int nc = n < N ? n : (N - 1);
    offB[ni] = (size_t)nc * K;
  }

  f32x4 acc[4][4];
#pragma unroll
  for (int mi = 0; mi < 4; ++mi)
#pragma unroll
    for (int ni = 0; ni < 4; ++ni) acc[mi][ni] = (f32x4){0.f, 0.f, 0.f, 0.f};

  for (int k0 = 0; k0 < K; k0 += 32) {
    bf16x8 ah[4], al[4];
#pragma unroll
    for (int mi = 0; mi < 4; ++mi) {
      ah[mi] = *(const bf16x8*)(Ahi + offA[mi] + k0 + koff);
      al[mi] = *(const bf16x8*)(Alo + offA[mi] + k0 + koff);
    }
#pragma unroll
    for (int ni = 0; ni < 4; ++ni) {
      const bf16x8 bh = *(const bf16x8*)(Whi + offB[ni] + k0 + koff);
      const bf16x8 bl = *(const bf16x8*)(Wlo + offB[ni] + k0 + koff);
#pragma unroll
      for (int mi = 0; mi < 4; ++mi) {
        acc[mi][ni] = __builtin_amdgcn_mfma_f32_16x16x32_bf16(ah[mi], bl, acc[mi][ni], 0, 0, 0);
        acc[mi][ni] = __builtin_amdgcn_mfma_f32_16x16x32_bf16(al[mi], bh, acc[mi][ni], 0, 0, 0);
        acc[mi][ni] = __builtin_amdgcn_mfma_f32_16x16x32_bf16(ah[mi], bh, acc[mi][ni], 0, 0, 0);
      }
    }
  }

  float bv[4];
#pragma unroll
  for (int ni = 0; ni < 4; ++ni) {
    int n = n0 + ni * 16 + lm;
    bv[ni] = bias[n < N ? n : (N - 1)];
  }

  if (FUSED == 0) {
    // Xg[t][n][b], t=m>>6, b=m&63 (t-tiles 64-aligned, N=2048)
#pragma unroll
    for (int mi = 0; mi < 4; ++mi) {
#pragma unroll
      for (int i = 0; i < 4; ++i) {
        const int m = m0 + mi * 16 + quad * 4 + i;
        if (m >= M) continue;
        const int t = m >> 6, b = m & 63;
        float* base = Xg + (size_t)t * 131072 + b;
#pragma unroll
        for (int ni = 0; ni < 4; ++ni) {
          const int n = n0 + ni * 16 + lm;
          base[(size_t)n * 64] = acc[mi][ni][i] + bv[ni];
        }
      }
    }
  } else {
    // row m = j*64+b (logits for decoder step j -> output (b, t=j+1))
#pragma unroll
    for (int mi = 0; mi < 4; ++mi) {
#pragma unroll
      for (int i = 0; i < 4; ++i) {
        const int m = m0 + mi * 16 + quad * 4 + i;
        if (m >= M) continue;
        const int j = m >> 6, b = m & 63;
        const int outrow = b * 128 + j + 1;
        if (mask[outrow] == 0) continue;
        const int r = idxmap[outrow];
        const uint32_t base7 = (uint32_t)(r * 64 + b) * 10000u;
        float best = -3.0e38f;
        int bestn = 0;
#pragma unroll
        for (int ni = 0; ni < 4; ++ni) {
          const int n = n0 + ni * 16 + lm;
          if (n < N) {
            const float u7 = jax_uniform(7u, base7 + (uint32_t)n);
            const float g = -logf(-logf(u7 + 1e-20f) + 1e-20f);
            const float z = acc[mi][ni][i] + bv[ni] + g;
            if (z > best) { best = z; bestn = n; }
          }
        }
        unsigned long long key = packkey(best, bestn);
#pragma unroll
        for (int s = 1; s < 16; s <<= 1) {
          const unsigned long long o = __shfl_xor(key, s, 64);
          if (o > key) key = o;
        }
        if (lm == 0) atomicMax(keys + outrow, key);
      }
    }
  }
}

// ---------------------------------------------------------------------------
// One LSTM recurrence step (UNCHANGED from verified R3 kernel).
// Xg [2048 cols][64 b] (col = gate*512+u); h,c: [512 u][64 b]; Whh [2048][512].
// ---------------------------------------------------------------------------
__global__ __launch_bounds__(128)
void lstm_step_kernel(const float* __restrict__ Xg,
                      const float* __restrict__ hprev,
                      const float* __restrict__ Whh,
                      float* __restrict__ cstate,
                      float* __restrict__ hout)
{
  __shared__ __align__(16) float ws[8][512];
  __shared__ __align__(16) float hs[4096];
  const int tid = threadIdx.x;
  const int b = tid & 63;
  const int ui = tid >> 6;
  const int U0 = blockIdx.x * 2;
  const int u = U0 + ui;

  {
    const int r = tid >> 4;
    const int lui = r >> 2, lg = r & 3;
    const float* wrow = Whh + (size_t)(lg * 512 + U0 + lui) * 512;
    const int kq = tid & 15;
#pragma unroll
    for (int i = 0; i < 8; ++i) {
      const int k = kq * 4 + i * 64;
      *(float4*)&ws[r][k] = *(const float4*)(wrow + k);
    }
  }

  const float x_i = Xg[(size_t)(0 * 512 + u) * 64 + b];
  const float x_f = Xg[(size_t)(1 * 512 + u) * 64 + b];
  const float x_g = Xg[(size_t)(2 * 512 + u) * 64 + b];
  const float x_o = Xg[(size_t)(3 * 512 + u) * 64 + b];
  const float c_old = cstate[(size_t)u * 64 + b];

  float4 pre[8];
#pragma unroll
  for (int i = 0; i < 8; ++i) pre[i] = ((const float4*)hprev)[tid + 128 * i];

  float a0 = 0.f, a1 = 0.f, a2 = 0.f, a3 = 0.f;
  for (int kc = 0; kc < 8; ++kc) {
    __syncthreads();
#pragma unroll
    for (int i = 0; i < 8; ++i) ((float4*)hs)[tid + 128 * i] = pre[i];
    __syncthreads();
    if (kc < 7) {
#pragma unroll
      for (int i = 0; i < 8; ++i)
        pre[i] = ((const float4*)hprev)[(kc + 1) * 1024 + tid + 128 * i];
    }
    const int kb = kc * 64;
#pragma unroll
    for (int kg = 0; kg < 16; ++kg) {
      const float h0 = hs[(kg * 4 + 0) * 64 + b];
      const float h1 = hs[(kg * 4 + 1) * 64 + b];
      const float h2 = hs[(kg * 4 + 2) * 64 + b];
      const float h3 = hs[(kg * 4 + 3) * 64 + b];
      const float4 w0 = *(const float4*)&ws[ui * 4 + 0][kb + kg * 4];
      const float4 w1 = *(const float4*)&ws[ui * 4 + 1][kb + kg * 4];
      const float4 w2 = *(const float4*)&ws[ui * 4 + 2][kb + kg * 4];
      const float4 w3 = *(const float4*)&ws[ui * 4 + 3][kb + kg * 4];
      a0 += h0 * w0.x + h1 * w0.y + h2 * w0.z + h3 * w0.w;
      a1 += h0 * w1.x + h1 * w1.y + h2 * w1.z + h3 * w1.w;
      a2 += h0 * w2.x + h1 * w2.y + h2 * w2.z + h3 * w2.w;
      a3 += h0 * w3.x + h1 * w3.y + h2 * w3.z + h3 * w3.w;
    }
  }

  const float zi = x_i + a0, zf = x_f + a1, zg = x_g + a2, zo = x_o + a3;
  const float I = 1.0f / (1.0f + expf(-zi));
  const float F = 1.0f / (1.0f + expf(-zf));
  const float G = tanhf(zg);
  const float O = 1.0f / (1.0f + expf(-zo));
  const float cn = F * c_old + I * G;
  cstate[(size_t)u * 64 + b] = cn;
  hout[(size_t)u * 64 + b] = O * tanhf(cn);
}

// ---------------------------------------------------------------------------
__global__ void maskscan_kernel(const int* __restrict__ mask,
                                int* __restrict__ idxmap)
{
  const int b = threadIdx.x;   // 64 threads
  int run = 0;
  for (int t = 0; t < 128; ++t) {
    idxmap[b * 128 + t] = run;
    run += mask[b * 128 + t];
  }
}

// masked t=0 rows: argmax(U42[b,v] + gumbel(U7 row 0 of scatter target))
__global__ __launch_bounds__(256)
void t0_kernel(const int* __restrict__ mask, unsigned long long* __restrict__ keys)
{
  const int b = blockIdx.x;
  const int row = b * 128;
  if (mask[row] == 0) return;
  const int tid = threadIdx.x;
  const uint32_t base = (uint32_t)b * 10000u;
  float best = -3.0e38f;
  int bestn = 0;
  for (int v = tid; v < 10000; v += 256) {
    const float u42 = jax_uniform(42u, base + (uint32_t)v);
    const float u7 = jax_uniform(7u, base + (uint32_t)v);
    const float g = -logf(-logf(u7 + 1e-20f) + 1e-20f);
    const float z = u42 + g;
    if (z > best) { best = z; bestn = v; }
  }
  __shared__ unsigned long long sk[256];
  sk[tid] = packkey(best, bestn);
  __syncthreads();
  for (int s = 128; s > 0; s >>= 1) {
    if (tid < s) { if (sk[tid + s] > sk[tid]) sk[tid] = sk[tid + s]; }
    __syncthreads();
  }
  if (tid == 0) keys[row] = sk[0];
}

__global__ __launch_bounds__(256)
void finalize_kernel(const unsigned long long* __restrict__ keys,
                     const int* __restrict__ mask,
                     const int* __restrict__ input_ids,
                     int* __restrict__ tokens)
{
  const int row = blockIdx.x * 256 + threadIdx.x;
  if (row < 8192) {
    tokens[row] = mask[row] ? (int)(0x7FFFFFFFu - (uint32_t)(keys[row] & 0xFFFFFFFFu))
                            : input_ids[row];
  }
}

__global__ __launch_bounds__(256)
void onehot_kernel(const int* __restrict__ tokens, float* __restrict__ out)
{
  const int row = blockIdx.x;
  const int tok = tokens[row];
  float4* orow = (float4*)(out + (size_t)row * 10000);
  for (int q = threadIdx.x; q < 2500; q += 256) {
    float4 v = make_float4(0.f, 0.f, 0.f, 0.f);
    const int v0 = q << 2;
    const unsigned d = (unsigned)(tok - v0);
    if (d < 4u) ((float*)&v)[d] = 1.0f;
    orow[q] = v;
  }
}

__global__ __launch_bounds__(256)
void zero_kernel(float* __restrict__ p, int n)
{
  const int i = blockIdx.x * 256 + threadIdx.x;
  if (i < n) p[i] = 0.f;
}

// ---------------------------------------------------------------------------
extern "C" void kernel_launch(void* const* d_in, const int* in_sizes, int n_in,
                              void* d_out, int out_size, void* d_ws, size_t ws_size,
                              hipStream_t stream)
{
  const int*   input_ids = (const int*)d_in[0];
  const int*   mask      = (const int*)d_in[1];
  const float* enc_embed = (const float*)d_in[3];
  const float* enc_Wih0  = (const float*)d_in[4];
  const float* enc_Whh0  = (const float*)d_in[5];
  const float* enc_b0    = (const float*)d_in[6];
  const float* enc_Wih1  = (const float*)d_in[7];
  const float* enc_Whh1  = (const float*)d_in[8];
  const float* enc_b1    = (const float*)d_in[9];
  const float* dec_embed = (const float*)d_in[10];
  const float* dec_Wih0  = (const float*)d_in[11];
  const float* dec_Whh0  = (const float*)d_in[12];
  const float* dec_b0    = (const float*)d_in[13];
  const float* dec_Wih1  = (const float*)d_in[14];
  const float* dec_Whh1  = (const float*)d_in[15];
  const float* dec_b1    = (const float*)d_in[16];
  const float* dec_Wout  = (const float*)d_in[17];
  const float* dec_bout  = (const float*)d_in[18];

  // ---- d_out doubles as scratch (327.68 MB); all consumed before onehot ----
  char* O = (char*)d_out;
  float*  Xg    = (float*)(O + 0);                    // 8192*2048 f32 (67.1MB)
  ushort* sThi  = (ushort*)(O + 67108864);            // seqT hi 8192*512
  ushort* sTlo  = (ushort*)(O + 75497472);
  ushort* eEh   = (ushort*)(O + 83886080);            // enc_embed split
  ushort* eEl   = (ushort*)(O + 89006080);
  ushort* dEh   = (ushort*)(O + 94126080);            // dec_embed split
  ushort* dEl   = (ushort*)(O + 99246080);
  ushort* eW0h  = (ushort*)(O + 104366080);
  ushort* eW0l  = (ushort*)(O + 105414656);
  ushort* eW1h  = (ushort*)(O + 106463232);
  ushort* eW1l  = (ushort*)(O + 108560384);
  ushort* dW0h  = (ushort*)(O + 110657536);
  ushort* dW0l  = (ushort*)(O + 111706112);
  ushort* dW1h  = (ushort*)(O + 112754688);
  ushort* dW1l  = (ushort*)(O + 114851840);
  ushort* Woh   = (ushort*)(O + 116948992);           // dec_Wout split
  ushort* Wol   = (ushort*)(O + 127188992);
  unsigned long long* keys = (unsigned long long*)(O + 137428992);  // 8192
  int*    idxmap = (int*)(O + 137494528);                            // 8192

  // ---- workspace (proven footprint from R3) ----
  float* seqA = (float*)d_ws;                         // 128*32768 f32
  float* zbuf = seqA + (size_t)128 * 32768;
  float* cA   = zbuf + 32768;
  float* cB   = cA + 32768;
  float* hp0  = cB + 32768;
  float* hp1  = hp0 + 32768;
  int* tokens = (int*)(hp1 + 32768);

  zero_kernel<<<384, 256, 0, stream>>>(zbuf, 3 * 32768);          // zbuf,cA,cB
  zero_kernel<<<64, 256, 0, stream>>>((float*)keys, 16384);       // keys
  maskscan_kernel<<<1, 64, 0, stream>>>(mask, idxmap);

  // ---- one-shot precision splits ----
  split_kernel<<<10000, 256, 0, stream>>>(enc_embed, eEh, eEl, 2560000);
  split_kernel<<<10000, 256, 0, stream>>>(dec_embed, dEh, dEl, 2560000);
  split_kernel<<<2048, 256, 0, stream>>>(enc_Wih0, eW0h, eW0l, 524288);
  split_kernel<<<4096, 256, 0, stream>>>(enc_Wih1, eW1h, eW1l, 1048576);
  split_kernel<<<2048, 256, 0, stream>>>(dec_Wih0, dW0h, dW0l, 524288);
  split_kernel<<<4096, 256, 0, stream>>>(dec_Wih1, dW1h, dW1l, 1048576);
  split_kernel<<<20000, 256, 0, stream>>>(dec_Wout, Woh, Wol, 5120000);

  // ---- encoder layer 0 ----
  gemm_split<1, 0><<<dim3(64, 16), 256, 0, stream>>>(
      eEh, eEl, input_ids, eW0h, eW0l, enc_b0, Xg,
      nullptr, nullptr, nullptr, 8192, 2048, 256);
  for (int t = 0; t < 128; ++t) {
    const float* hi = (t == 0) ? zbuf : (seqA + (size_t)(t - 1) * 32768);
    lstm_step_kernel<<<256, 128, 0, stream>>>(
        Xg + (size_t)t * 131072, hi, enc_Whh0, cA, seqA + (size_t)t * 32768);
  }

  // ---- encoder layer 1 (final state only) ----
  transpose_split_kernel<<<512, 256, 0, stream>>>(seqA, sThi, sTlo);
  gemm_split<0, 0><<<dim3(64, 16), 256, 0, stream>>>(
      sThi, sTlo, nullptr, eW1h, eW1l, enc_b1, Xg,
      nullptr, nullptr, nullptr, 8192, 2048, 512);
  for (int t = 0; t < 128; ++t) {
    const float* hi = (t == 0) ? zbuf : ((t & 1) ? hp0 : hp1);
    float* ho = (t & 1) ? hp1 : hp0;                  // t=127 -> hp1
    lstm_step_kernel<<<256, 128, 0, stream>>>(
        Xg + (size_t)t * 131072, hi, enc_Whh1, cB, ho);
  }

  // ---- decoder layer 0: init (h,c) = enc L0 finals ----
  gemm_split<1, 0><<<dim3(64, 16), 256, 0, stream>>>(
      dEh, dEl, input_ids, dW0h, dW0l, dec_b0, Xg,
      nullptr, nullptr, nullptr, 8128, 2048, 256);
  for (int j = 0; j < 127; ++j) {
    const float* hi = (j == 0) ? (seqA + (size_t)127 * 32768)
                               : (seqA + (size_t)(j - 1) * 32768);
    lstm_step_kernel<<<256, 128, 0, stream>>>(
        Xg + (size_t)j * 131072, hi, dec_Whh0, cA, seqA + (size_t)j * 32768);
  }

  // ---- decoder layer 1: init (h,c) = enc L1 finals ----
  transpose_split_kernel<<<508, 256, 0, stream>>>(seqA, sThi, sTlo);
  gemm_split<0, 0><<<dim3(64, 16), 256, 0, stream>>>(
      sThi, sTlo, nullptr, dW1h, dW1l, dec_b1, Xg,
      nullptr, nullptr, nullptr, 8128, 2048, 512);
  for (int j = 0; j < 127; ++j) {
    const float* hi = (j == 0) ? hp1 : (seqA + (size_t)(j - 1) * 32768);
    lstm_step_kernel<<<256, 128, 0, stream>>>(
        Xg + (size_t)j * 131072, hi, dec_Whh1, cB, seqA + (size_t)j * 32768);
  }

  // ---- fused logits + gumbel-argmax (no logits materialization) ----
  transpose_split_kernel<<<508, 256, 0, stream>>>(seqA, sThi, sTlo);
  gemm_split<0, 1><<<dim3(64, 79), 256, 0, stream>>>(
      sThi, sTlo, nullptr, Woh, Wol, dec_bout, nullptr,
      mask, idxmap, keys, 8128, 10000, 512);
  t0_kernel<<<64, 256, 0, stream>>>(mask, keys);

  // ---- tokens -> one-hot output ----
  finalize_kernel<<<32, 256, 0, stream>>>(keys, mask, input_ids, tokens);
  onehot_kernel<<<8192, 256, 0, stream>>>(tokens, (float*)d_out);
}